// Round 3
// baseline (427.065 us; speedup 1.0000x reference)
//
#include <hip/hip_runtime.h>
#include <math.h>

// Capsule dynamic routing — coalesced W + 2-batch W reuse.
// x: [B=256, R=1152, I=8] f32
// W: [C=10, R=1152, I=8, O=16] f32
// out: [B=256, C=10, O=16] f32
//
// One block per (c, b-pair). 768 threads = 192 groups of 4 lanes.
// Group g owns rows r = g + j*192 (j=0..5); lane q=t&3 owns o-quad q*4..q*4+3.
// Each W float4 is loaded once and feeds FMAs for BOTH batches (G=2),
// halving on-chip W traffic vs one-b-per-block.

#define C_CAPS 10
#define B_SZ   256
#define R_SZ   1152
#define I_SZ   8
#define O_SZ   16
#define G_B    2         // batches per block
#define T_THREADS 768
#define NGROUP 192       // T/4 groups
#define RPT 6            // rows per group = R / NGROUP
#define NW 12            // waves per block

__global__ __launch_bounds__(T_THREADS, 4) void capsule_kernel(
    const float* __restrict__ x,
    const float* __restrict__ w,
    float* __restrict__ out)
{
    const int c  = blockIdx.x >> 7;        // / (B/G)
    const int bb = blockIdx.x & 127;       // % (B/G)
    const int b0 = bb * G_B;
    const int t = (int)threadIdx.x;
    const int lane = t & 63;
    const int wid = t >> 6;
    const int q = t & 3;                   // o-quad index
    const int g = t >> 2;                  // group id 0..191

    __shared__ float red_max[NW][G_B];
    __shared__ float red_sum[NW][G_B];
    __shared__ float red_s[NW][G_B][4][4];

    // ---- priors: P[gb][j][k] = priors[b0+gb][r = g + j*192][o = q*4+k] ----
    float P[G_B][RPT][4];
    #pragma unroll
    for (int j = 0; j < RPT; ++j) {
        const int r = g + j * NGROUP;
        const float* xp = x + ((size_t)b0 * R_SZ + r) * I_SZ;
        // batch 0 and 1 x-rows (broadcast within 4-lane group)
        const float4 x0a = *(const float4*)(xp);
        const float4 x0b = *(const float4*)(xp + 4);
        const float4 x1a = *(const float4*)(xp + (size_t)R_SZ * I_SZ);
        const float4 x1b = *(const float4*)(xp + (size_t)R_SZ * I_SZ + 4);
        const float xi0[I_SZ] = {x0a.x, x0a.y, x0a.z, x0a.w, x0b.x, x0b.y, x0b.z, x0b.w};
        const float xi1[I_SZ] = {x1a.x, x1a.y, x1a.z, x1a.w, x1b.x, x1b.y, x1b.z, x1b.w};

        const float* wr = w + ((size_t)c * R_SZ + r) * (I_SZ * O_SZ) + q * 4;
        float a00 = 0.f, a01 = 0.f, a02 = 0.f, a03 = 0.f;
        float a10 = 0.f, a11 = 0.f, a12 = 0.f, a13 = 0.f;
        #pragma unroll
        for (int i = 0; i < I_SZ; ++i) {
            const float4 wv = *(const float4*)(wr + i * O_SZ);
            a00 = fmaf(xi0[i], wv.x, a00);
            a01 = fmaf(xi0[i], wv.y, a01);
            a02 = fmaf(xi0[i], wv.z, a02);
            a03 = fmaf(xi0[i], wv.w, a03);
            a10 = fmaf(xi1[i], wv.x, a10);
            a11 = fmaf(xi1[i], wv.y, a11);
            a12 = fmaf(xi1[i], wv.z, a12);
            a13 = fmaf(xi1[i], wv.w, a13);
        }
        P[0][j][0] = a00; P[0][j][1] = a01; P[0][j][2] = a02; P[0][j][3] = a03;
        P[1][j][0] = a10; P[1][j][1] = a11; P[1][j][2] = a12; P[1][j][3] = a13;
    }

    float logit[G_B][RPT];
    #pragma unroll
    for (int gb = 0; gb < G_B; ++gb)
        #pragma unroll
        for (int j = 0; j < RPT; ++j) logit[gb][j] = 0.0f;

    float outq[G_B][4];

    for (int it = 0; it < 3; ++it) {
        // ---- probs over r ----
        float p[G_B][RPT];
        if (it == 0) {
            const float u = 1.0f / (float)R_SZ;
            #pragma unroll
            for (int gb = 0; gb < G_B; ++gb)
                #pragma unroll
                for (int j = 0; j < RPT; ++j) p[gb][j] = u;
        } else {
            #pragma unroll
            for (int gb = 0; gb < G_B; ++gb) {
                float lm = logit[gb][0];
                #pragma unroll
                for (int j = 1; j < RPT; ++j) lm = fmaxf(lm, logit[gb][j]);
                #pragma unroll
                for (int m = 4; m <= 32; m <<= 1) lm = fmaxf(lm, __shfl_xor(lm, m, 64));
                if (lane == 0) red_max[wid][gb] = lm;
            }
            __syncthreads();
            #pragma unroll
            for (int gb = 0; gb < G_B; ++gb) {
                float gm = red_max[0][gb];
                #pragma unroll
                for (int k = 1; k < NW; ++k) gm = fmaxf(gm, red_max[k][gb]);
                float zp = 0.0f;
                #pragma unroll
                for (int j = 0; j < RPT; ++j) {
                    p[gb][j] = expf(logit[gb][j] - gm);
                    zp += p[gb][j];
                }
                #pragma unroll
                for (int m = 4; m <= 32; m <<= 1) zp += __shfl_xor(zp, m, 64);
                if (lane == 0) red_sum[wid][gb] = zp;
            }
            __syncthreads();
            #pragma unroll
            for (int gb = 0; gb < G_B; ++gb) {
                float Z = red_sum[0][gb];
                #pragma unroll
                for (int k = 1; k < NW; ++k) Z += red_sum[k][gb];
                const float invZ = 1.0f / Z;
                #pragma unroll
                for (int j = 0; j < RPT; ++j) p[gb][j] *= invZ;
            }
        }

        // ---- s and squash per batch ----
        #pragma unroll
        for (int gb = 0; gb < G_B; ++gb) {
            float sa[4] = {0.f, 0.f, 0.f, 0.f};
            #pragma unroll
            for (int j = 0; j < RPT; ++j) {
                sa[0] = fmaf(p[gb][j], P[gb][j][0], sa[0]);
                sa[1] = fmaf(p[gb][j], P[gb][j][1], sa[1]);
                sa[2] = fmaf(p[gb][j], P[gb][j][2], sa[2]);
                sa[3] = fmaf(p[gb][j], P[gb][j][3], sa[3]);
            }
            #pragma unroll
            for (int m = 4; m <= 32; m <<= 1) {
                sa[0] += __shfl_xor(sa[0], m, 64);
                sa[1] += __shfl_xor(sa[1], m, 64);
                sa[2] += __shfl_xor(sa[2], m, 64);
                sa[3] += __shfl_xor(sa[3], m, 64);
            }
            if (lane < 4) {
                red_s[wid][gb][lane][0] = sa[0];
                red_s[wid][gb][lane][1] = sa[1];
                red_s[wid][gb][lane][2] = sa[2];
                red_s[wid][gb][lane][3] = sa[3];
            }
        }
        __syncthreads();

        #pragma unroll
        for (int gb = 0; gb < G_B; ++gb) {
            float sv[4];
            #pragma unroll
            for (int k = 0; k < 4; ++k) {
                float v = red_s[0][gb][q][k];
                #pragma unroll
                for (int ww = 1; ww < NW; ++ww) v += red_s[ww][gb][q][k];
                sv[k] = v;
            }
            float nrm = sv[0]*sv[0] + sv[1]*sv[1] + sv[2]*sv[2] + sv[3]*sv[3];
            nrm += __shfl_xor(nrm, 1, 64);
            nrm += __shfl_xor(nrm, 2, 64);
            const float scale = nrm / ((1.0f + nrm) * sqrtf(nrm));
            #pragma unroll
            for (int k = 0; k < 4; ++k) outq[gb][k] = scale * sv[k];
        }

        // ---- logit update (iters 0,1) ----
        if (it < 2) {
            #pragma unroll
            for (int gb = 0; gb < G_B; ++gb) {
                #pragma unroll
                for (int j = 0; j < RPT; ++j) {
                    float d = P[gb][j][0]*outq[gb][0] + P[gb][j][1]*outq[gb][1]
                            + P[gb][j][2]*outq[gb][2] + P[gb][j][3]*outq[gb][3];
                    d += __shfl_xor(d, 1, 64);
                    d += __shfl_xor(d, 2, 64);
                    logit[gb][j] += d;
                }
            }
        }
        __syncthreads();
    }

    // ---- write out[b0+gb, c, :]: threads 0..3 hold quads 0..3 ----
    if (t < 4) {
        #pragma unroll
        for (int gb = 0; gb < G_B; ++gb) {
            float* op = out + ((size_t)(b0 + gb) * C_CAPS + c) * O_SZ + q * 4;
            *(float4*)op = make_float4(outq[gb][0], outq[gb][1], outq[gb][2], outq[gb][3]);
        }
    }
}

extern "C" void kernel_launch(void* const* d_in, const int* in_sizes, int n_in,
                              void* d_out, int out_size, void* d_ws, size_t ws_size,
                              hipStream_t stream) {
    const float* x = (const float*)d_in[0];
    const float* w = (const float*)d_in[1];
    float* out = (float*)d_out;
    dim3 grid(C_CAPS * (B_SZ / G_B));
    dim3 block(T_THREADS);
    hipLaunchKernelGGL(capsule_kernel, grid, block, 0, stream, x, w, out);
}

// Round 4
// 322.058 us; speedup vs baseline: 1.3260x; 1.3260x over previous
//
#include <hip/hip_runtime.h>
#include <math.h>

// Capsule dynamic routing — coalesced W + 2-batch W reuse.
// Round-4 change: __launch_bounds__(768, 3) instead of (768, 4).
// (768,4) forced a 64-VGPR cap -> ~50 floats/thread spilled to scratch ->
// 1.7 GB of HBM scratch traffic and a 4.4x regression. 12-wave blocks are
// 3 waves/EU, so min=3 is the matching occupancy; cap ~170 VGPR, need ~110.
//
// x: [B=256, R=1152, I=8] f32
// W: [C=10, R=1152, I=8, O=16] f32
// out: [B=256, C=10, O=16] f32
//
// One block per (c, b-pair). 768 threads = 192 groups of 4 lanes.
// Group g owns rows r = g + j*192 (j=0..5); lane q=t&3 owns o-quad q*4..q*4+3.
// Each W float4 is loaded once and feeds FMAs for BOTH batches (G=2).

#define C_CAPS 10
#define B_SZ   256
#define R_SZ   1152
#define I_SZ   8
#define O_SZ   16
#define G_B    2         // batches per block
#define T_THREADS 768
#define NGROUP 192       // T/4 groups
#define RPT 6            // rows per group = R / NGROUP
#define NW 12            // waves per block

__global__ __launch_bounds__(T_THREADS, 3) void capsule_kernel(
    const float* __restrict__ x,
    const float* __restrict__ w,
    float* __restrict__ out)
{
    const int c  = blockIdx.x >> 7;        // / (B/G)
    const int bb = blockIdx.x & 127;       // % (B/G)
    const int b0 = bb * G_B;
    const int t = (int)threadIdx.x;
    const int lane = t & 63;
    const int wid = t >> 6;
    const int q = t & 3;                   // o-quad index
    const int g = t >> 2;                  // group id 0..191

    __shared__ float red_max[NW][G_B];
    __shared__ float red_sum[NW][G_B];
    __shared__ float red_s[NW][G_B][4][4];

    // ---- priors: P[gb][j][k] = priors[b0+gb][r = g + j*192][o = q*4+k] ----
    float P[G_B][RPT][4];
    #pragma unroll
    for (int j = 0; j < RPT; ++j) {
        const int r = g + j * NGROUP;
        const float* xp = x + ((size_t)b0 * R_SZ + r) * I_SZ;
        // batch 0 and 1 x-rows (broadcast within 4-lane group)
        const float4 x0a = *(const float4*)(xp);
        const float4 x0b = *(const float4*)(xp + 4);
        const float4 x1a = *(const float4*)(xp + (size_t)R_SZ * I_SZ);
        const float4 x1b = *(const float4*)(xp + (size_t)R_SZ * I_SZ + 4);
        const float xi0[I_SZ] = {x0a.x, x0a.y, x0a.z, x0a.w, x0b.x, x0b.y, x0b.z, x0b.w};
        const float xi1[I_SZ] = {x1a.x, x1a.y, x1a.z, x1a.w, x1b.x, x1b.y, x1b.z, x1b.w};

        const float* wr = w + ((size_t)c * R_SZ + r) * (I_SZ * O_SZ) + q * 4;
        float a00 = 0.f, a01 = 0.f, a02 = 0.f, a03 = 0.f;
        float a10 = 0.f, a11 = 0.f, a12 = 0.f, a13 = 0.f;
        #pragma unroll
        for (int i = 0; i < I_SZ; ++i) {
            const float4 wv = *(const float4*)(wr + i * O_SZ);
            a00 = fmaf(xi0[i], wv.x, a00);
            a01 = fmaf(xi0[i], wv.y, a01);
            a02 = fmaf(xi0[i], wv.z, a02);
            a03 = fmaf(xi0[i], wv.w, a03);
            a10 = fmaf(xi1[i], wv.x, a10);
            a11 = fmaf(xi1[i], wv.y, a11);
            a12 = fmaf(xi1[i], wv.z, a12);
            a13 = fmaf(xi1[i], wv.w, a13);
        }
        P[0][j][0] = a00; P[0][j][1] = a01; P[0][j][2] = a02; P[0][j][3] = a03;
        P[1][j][0] = a10; P[1][j][1] = a11; P[1][j][2] = a12; P[1][j][3] = a13;
    }

    float logit[G_B][RPT];
    #pragma unroll
    for (int gb = 0; gb < G_B; ++gb)
        #pragma unroll
        for (int j = 0; j < RPT; ++j) logit[gb][j] = 0.0f;

    float outq[G_B][4];

    for (int it = 0; it < 3; ++it) {
        // ---- probs over r ----
        float p[G_B][RPT];
        if (it == 0) {
            const float u = 1.0f / (float)R_SZ;
            #pragma unroll
            for (int gb = 0; gb < G_B; ++gb)
                #pragma unroll
                for (int j = 0; j < RPT; ++j) p[gb][j] = u;
        } else {
            #pragma unroll
            for (int gb = 0; gb < G_B; ++gb) {
                float lm = logit[gb][0];
                #pragma unroll
                for (int j = 1; j < RPT; ++j) lm = fmaxf(lm, logit[gb][j]);
                #pragma unroll
                for (int m = 4; m <= 32; m <<= 1) lm = fmaxf(lm, __shfl_xor(lm, m, 64));
                if (lane == 0) red_max[wid][gb] = lm;
            }
            __syncthreads();
            #pragma unroll
            for (int gb = 0; gb < G_B; ++gb) {
                float gm = red_max[0][gb];
                #pragma unroll
                for (int k = 1; k < NW; ++k) gm = fmaxf(gm, red_max[k][gb]);
                float zp = 0.0f;
                #pragma unroll
                for (int j = 0; j < RPT; ++j) {
                    p[gb][j] = expf(logit[gb][j] - gm);
                    zp += p[gb][j];
                }
                #pragma unroll
                for (int m = 4; m <= 32; m <<= 1) zp += __shfl_xor(zp, m, 64);
                if (lane == 0) red_sum[wid][gb] = zp;
            }
            __syncthreads();
            #pragma unroll
            for (int gb = 0; gb < G_B; ++gb) {
                float Z = red_sum[0][gb];
                #pragma unroll
                for (int k = 1; k < NW; ++k) Z += red_sum[k][gb];
                const float invZ = 1.0f / Z;
                #pragma unroll
                for (int j = 0; j < RPT; ++j) p[gb][j] *= invZ;
            }
        }

        // ---- s and squash per batch ----
        #pragma unroll
        for (int gb = 0; gb < G_B; ++gb) {
            float sa[4] = {0.f, 0.f, 0.f, 0.f};
            #pragma unroll
            for (int j = 0; j < RPT; ++j) {
                sa[0] = fmaf(p[gb][j], P[gb][j][0], sa[0]);
                sa[1] = fmaf(p[gb][j], P[gb][j][1], sa[1]);
                sa[2] = fmaf(p[gb][j], P[gb][j][2], sa[2]);
                sa[3] = fmaf(p[gb][j], P[gb][j][3], sa[3]);
            }
            #pragma unroll
            for (int m = 4; m <= 32; m <<= 1) {
                sa[0] += __shfl_xor(sa[0], m, 64);
                sa[1] += __shfl_xor(sa[1], m, 64);
                sa[2] += __shfl_xor(sa[2], m, 64);
                sa[3] += __shfl_xor(sa[3], m, 64);
            }
            if (lane < 4) {
                red_s[wid][gb][lane][0] = sa[0];
                red_s[wid][gb][lane][1] = sa[1];
                red_s[wid][gb][lane][2] = sa[2];
                red_s[wid][gb][lane][3] = sa[3];
            }
        }
        __syncthreads();

        #pragma unroll
        for (int gb = 0; gb < G_B; ++gb) {
            float sv[4];
            #pragma unroll
            for (int k = 0; k < 4; ++k) {
                float v = red_s[0][gb][q][k];
                #pragma unroll
                for (int ww = 1; ww < NW; ++ww) v += red_s[ww][gb][q][k];
                sv[k] = v;
            }
            float nrm = sv[0]*sv[0] + sv[1]*sv[1] + sv[2]*sv[2] + sv[3]*sv[3];
            nrm += __shfl_xor(nrm, 1, 64);
            nrm += __shfl_xor(nrm, 2, 64);
            const float scale = nrm / ((1.0f + nrm) * sqrtf(nrm));
            #pragma unroll
            for (int k = 0; k < 4; ++k) outq[gb][k] = scale * sv[k];
        }

        // ---- logit update (iters 0,1) ----
        if (it < 2) {
            #pragma unroll
            for (int gb = 0; gb < G_B; ++gb) {
                #pragma unroll
                for (int j = 0; j < RPT; ++j) {
                    float d = P[gb][j][0]*outq[gb][0] + P[gb][j][1]*outq[gb][1]
                            + P[gb][j][2]*outq[gb][2] + P[gb][j][3]*outq[gb][3];
                    d += __shfl_xor(d, 1, 64);
                    d += __shfl_xor(d, 2, 64);
                    logit[gb][j] += d;
                }
            }
        }
        __syncthreads();
    }

    // ---- write out[b0+gb, c, :]: threads 0..3 hold quads 0..3 ----
    if (t < 4) {
        #pragma unroll
        for (int gb = 0; gb < G_B; ++gb) {
            float* op = out + ((size_t)(b0 + gb) * C_CAPS + c) * O_SZ + q * 4;
            *(float4*)op = make_float4(outq[gb][0], outq[gb][1], outq[gb][2], outq[gb][3]);
        }
    }
}

extern "C" void kernel_launch(void* const* d_in, const int* in_sizes, int n_in,
                              void* d_out, int out_size, void* d_ws, size_t ws_size,
                              hipStream_t stream) {
    const float* x = (const float*)d_in[0];
    const float* w = (const float*)d_in[1];
    float* out = (float*)d_out;
    dim3 grid(C_CAPS * (B_SZ / G_B));
    dim3 block(T_THREADS);
    hipLaunchKernelGGL(capsule_kernel, grid, block, 0, stream, x, w, out);
}

// Round 5
// 282.910 us; speedup vs baseline: 1.5095x; 1.1384x over previous
//
#include <hip/hip_runtime.h>
#include <math.h>

// Capsule dynamic routing — coalesced W + 2-batch W reuse, NO launch_bounds.
// Rounds 3/4 lesson: __launch_bounds__(768,{4,3}) capped VGPRs at 64/84 and
// forced ~700MB-1.7GB of scratch spill traffic. This round: 384-thread blocks
// (round-2's clean shape), G=2, and no launch_bounds so the allocator can use
// the ~150-200 VGPRs the per-thread state (P[2][12][4]) actually needs.
//
// x: [B=256, R=1152, I=8] f32
// W: [C=10, R=1152, I=8, O=16] f32
// out: [B=256, C=10, O=16] f32
//
// One block per (c, b-pair). 384 threads = 96 groups of 4 lanes.
// Group g owns rows r = g + j*96 (j=0..11); lane q=t&3 owns o-quad.
// Each W float4 loaded once feeds FMAs for BOTH batches.

#define C_CAPS 10
#define B_SZ   256
#define R_SZ   1152
#define I_SZ   8
#define O_SZ   16
#define G_B    2         // batches per block
#define T_THREADS 384
#define NGROUP 96        // T/4 groups
#define RPT 12           // rows per group = R / NGROUP
#define NW 6             // waves per block

__global__ void capsule_kernel(
    const float* __restrict__ x,
    const float* __restrict__ w,
    float* __restrict__ out)
{
    const int c  = blockIdx.x >> 7;        // / (B/G)
    const int bb = blockIdx.x & 127;       // % (B/G)
    const int b0 = bb * G_B;
    const int t = (int)threadIdx.x;
    const int lane = t & 63;
    const int wid = t >> 6;
    const int q = t & 3;                   // o-quad index
    const int g = t >> 2;                  // group id 0..95

    __shared__ float red_max[NW][G_B];
    __shared__ float red_sum[NW][G_B];
    __shared__ float red_s[NW][G_B][4][4];

    // ---- priors: P[gb][j][k] = priors[b0+gb][r = g + j*96][o = q*4+k] ----
    float P[G_B][RPT][4];
    #pragma unroll
    for (int j = 0; j < RPT; ++j) {
        const int r = g + j * NGROUP;
        const float* xp = x + ((size_t)b0 * R_SZ + r) * I_SZ;
        const float4 x0a = *(const float4*)(xp);
        const float4 x0b = *(const float4*)(xp + 4);
        const float4 x1a = *(const float4*)(xp + (size_t)R_SZ * I_SZ);
        const float4 x1b = *(const float4*)(xp + (size_t)R_SZ * I_SZ + 4);
        const float xi0[I_SZ] = {x0a.x, x0a.y, x0a.z, x0a.w, x0b.x, x0b.y, x0b.z, x0b.w};
        const float xi1[I_SZ] = {x1a.x, x1a.y, x1a.z, x1a.w, x1b.x, x1b.y, x1b.z, x1b.w};

        const float* wr = w + ((size_t)c * R_SZ + r) * (I_SZ * O_SZ) + q * 4;
        float a00 = 0.f, a01 = 0.f, a02 = 0.f, a03 = 0.f;
        float a10 = 0.f, a11 = 0.f, a12 = 0.f, a13 = 0.f;
        #pragma unroll
        for (int i = 0; i < I_SZ; ++i) {
            const float4 wv = *(const float4*)(wr + i * O_SZ);
            a00 = fmaf(xi0[i], wv.x, a00);
            a01 = fmaf(xi0[i], wv.y, a01);
            a02 = fmaf(xi0[i], wv.z, a02);
            a03 = fmaf(xi0[i], wv.w, a03);
            a10 = fmaf(xi1[i], wv.x, a10);
            a11 = fmaf(xi1[i], wv.y, a11);
            a12 = fmaf(xi1[i], wv.z, a12);
            a13 = fmaf(xi1[i], wv.w, a13);
        }
        P[0][j][0] = a00; P[0][j][1] = a01; P[0][j][2] = a02; P[0][j][3] = a03;
        P[1][j][0] = a10; P[1][j][1] = a11; P[1][j][2] = a12; P[1][j][3] = a13;
    }

    float logit[G_B][RPT];
    #pragma unroll
    for (int gb = 0; gb < G_B; ++gb)
        #pragma unroll
        for (int j = 0; j < RPT; ++j) logit[gb][j] = 0.0f;

    float outq[G_B][4];

    for (int it = 0; it < 3; ++it) {
        // ---- probs over r ----
        float p[G_B][RPT];
        if (it == 0) {
            const float u = 1.0f / (float)R_SZ;
            #pragma unroll
            for (int gb = 0; gb < G_B; ++gb)
                #pragma unroll
                for (int j = 0; j < RPT; ++j) p[gb][j] = u;
        } else {
            #pragma unroll
            for (int gb = 0; gb < G_B; ++gb) {
                float lm = logit[gb][0];
                #pragma unroll
                for (int j = 1; j < RPT; ++j) lm = fmaxf(lm, logit[gb][j]);
                #pragma unroll
                for (int m = 4; m <= 32; m <<= 1) lm = fmaxf(lm, __shfl_xor(lm, m, 64));
                if (lane == 0) red_max[wid][gb] = lm;
            }
            __syncthreads();
            #pragma unroll
            for (int gb = 0; gb < G_B; ++gb) {
                float gm = red_max[0][gb];
                #pragma unroll
                for (int k = 1; k < NW; ++k) gm = fmaxf(gm, red_max[k][gb]);
                float zp = 0.0f;
                #pragma unroll
                for (int j = 0; j < RPT; ++j) {
                    p[gb][j] = expf(logit[gb][j] - gm);
                    zp += p[gb][j];
                }
                #pragma unroll
                for (int m = 4; m <= 32; m <<= 1) zp += __shfl_xor(zp, m, 64);
                if (lane == 0) red_sum[wid][gb] = zp;
            }
            __syncthreads();
            #pragma unroll
            for (int gb = 0; gb < G_B; ++gb) {
                float Z = red_sum[0][gb];
                #pragma unroll
                for (int k = 1; k < NW; ++k) Z += red_sum[k][gb];
                const float invZ = 1.0f / Z;
                #pragma unroll
                for (int j = 0; j < RPT; ++j) p[gb][j] *= invZ;
            }
        }

        // ---- s and squash per batch ----
        #pragma unroll
        for (int gb = 0; gb < G_B; ++gb) {
            float sa[4] = {0.f, 0.f, 0.f, 0.f};
            #pragma unroll
            for (int j = 0; j < RPT; ++j) {
                sa[0] = fmaf(p[gb][j], P[gb][j][0], sa[0]);
                sa[1] = fmaf(p[gb][j], P[gb][j][1], sa[1]);
                sa[2] = fmaf(p[gb][j], P[gb][j][2], sa[2]);
                sa[3] = fmaf(p[gb][j], P[gb][j][3], sa[3]);
            }
            #pragma unroll
            for (int m = 4; m <= 32; m <<= 1) {
                sa[0] += __shfl_xor(sa[0], m, 64);
                sa[1] += __shfl_xor(sa[1], m, 64);
                sa[2] += __shfl_xor(sa[2], m, 64);
                sa[3] += __shfl_xor(sa[3], m, 64);
            }
            if (lane < 4) {
                red_s[wid][gb][lane][0] = sa[0];
                red_s[wid][gb][lane][1] = sa[1];
                red_s[wid][gb][lane][2] = sa[2];
                red_s[wid][gb][lane][3] = sa[3];
            }
        }
        __syncthreads();

        #pragma unroll
        for (int gb = 0; gb < G_B; ++gb) {
            float sv[4];
            #pragma unroll
            for (int k = 0; k < 4; ++k) {
                float v = red_s[0][gb][q][k];
                #pragma unroll
                for (int ww = 1; ww < NW; ++ww) v += red_s[ww][gb][q][k];
                sv[k] = v;
            }
            float nrm = sv[0]*sv[0] + sv[1]*sv[1] + sv[2]*sv[2] + sv[3]*sv[3];
            nrm += __shfl_xor(nrm, 1, 64);
            nrm += __shfl_xor(nrm, 2, 64);
            const float scale = nrm / ((1.0f + nrm) * sqrtf(nrm));
            #pragma unroll
            for (int k = 0; k < 4; ++k) outq[gb][k] = scale * sv[k];
        }

        // ---- logit update (iters 0,1) ----
        if (it < 2) {
            #pragma unroll
            for (int gb = 0; gb < G_B; ++gb) {
                #pragma unroll
                for (int j = 0; j < RPT; ++j) {
                    float d = P[gb][j][0]*outq[gb][0] + P[gb][j][1]*outq[gb][1]
                            + P[gb][j][2]*outq[gb][2] + P[gb][j][3]*outq[gb][3];
                    d += __shfl_xor(d, 1, 64);
                    d += __shfl_xor(d, 2, 64);
                    logit[gb][j] += d;
                }
            }
        }
        __syncthreads();
    }

    // ---- write out[b0+gb, c, :]: threads 0..3 hold quads 0..3 ----
    if (t < 4) {
        #pragma unroll
        for (int gb = 0; gb < G_B; ++gb) {
            float* op = out + ((size_t)(b0 + gb) * C_CAPS + c) * O_SZ + q * 4;
            *(float4*)op = make_float4(outq[gb][0], outq[gb][1], outq[gb][2], outq[gb][3]);
        }
    }
}

extern "C" void kernel_launch(void* const* d_in, const int* in_sizes, int n_in,
                              void* d_out, int out_size, void* d_ws, size_t ws_size,
                              hipStream_t stream) {
    const float* x = (const float*)d_in[0];
    const float* w = (const float*)d_in[1];
    float* out = (float*)d_out;
    dim3 grid(C_CAPS * (B_SZ / G_B));
    dim3 block(T_THREADS);
    hipLaunchKernelGGL(capsule_kernel, grid, block, 0, stream, x, w, out);
}

// Round 6
// 107.329 us; speedup vs baseline: 3.9790x; 2.6359x over previous
//
#include <hip/hip_runtime.h>
#include <math.h>

// Capsule dynamic routing — coalesced W + 2-batch W reuse.
// Register-allocator saga: (768,4)->64 VGPR cap, (768,3)->84, no-bounds->64;
// empirical rule: cap = 512/(2*min_waves_per_eu); no-bounds defaults high.
// This round: __launch_bounds__(384, 1) -> cap 256 VGPR; state needs ~200.
//
// x: [B=256, R=1152, I=8] f32
// W: [C=10, R=1152, I=8, O=16] f32
// out: [B=256, C=10, O=16] f32
//
// One block per (c, b-pair). 384 threads = 96 groups of 4 lanes.
// Group g owns rows r = g + j*96 (j=0..11); lane q=t&3 owns o-quad.
// Each W float4 loaded once feeds FMAs for BOTH batches.

#define C_CAPS 10
#define B_SZ   256
#define R_SZ   1152
#define I_SZ   8
#define O_SZ   16
#define G_B    2         // batches per block
#define T_THREADS 384
#define NGROUP 96        // T/4 groups
#define RPT 12           // rows per group = R / NGROUP
#define NW 6             // waves per block

__global__ __launch_bounds__(T_THREADS, 1) void capsule_kernel(
    const float* __restrict__ x,
    const float* __restrict__ w,
    float* __restrict__ out)
{
    const int c  = blockIdx.x >> 7;        // / (B/G)
    const int bb = blockIdx.x & 127;       // % (B/G)
    const int b0 = bb * G_B;
    const int t = (int)threadIdx.x;
    const int lane = t & 63;
    const int wid = t >> 6;
    const int q = t & 3;                   // o-quad index
    const int g = t >> 2;                  // group id 0..95

    __shared__ float red_max[NW][G_B];
    __shared__ float red_sum[NW][G_B];
    __shared__ float red_s[NW][G_B][4][4];

    // ---- priors: P[gb][j][k] = priors[b0+gb][r = g + j*96][o = q*4+k] ----
    float P[G_B][RPT][4];
    #pragma unroll
    for (int j = 0; j < RPT; ++j) {
        const int r = g + j * NGROUP;
        const float* xp = x + ((size_t)b0 * R_SZ + r) * I_SZ;
        const float4 x0a = *(const float4*)(xp);
        const float4 x0b = *(const float4*)(xp + 4);
        const float4 x1a = *(const float4*)(xp + (size_t)R_SZ * I_SZ);
        const float4 x1b = *(const float4*)(xp + (size_t)R_SZ * I_SZ + 4);
        const float xi0[I_SZ] = {x0a.x, x0a.y, x0a.z, x0a.w, x0b.x, x0b.y, x0b.z, x0b.w};
        const float xi1[I_SZ] = {x1a.x, x1a.y, x1a.z, x1a.w, x1b.x, x1b.y, x1b.z, x1b.w};

        const float* wr = w + ((size_t)c * R_SZ + r) * (I_SZ * O_SZ) + q * 4;
        float a00 = 0.f, a01 = 0.f, a02 = 0.f, a03 = 0.f;
        float a10 = 0.f, a11 = 0.f, a12 = 0.f, a13 = 0.f;
        #pragma unroll
        for (int i = 0; i < I_SZ; ++i) {
            const float4 wv = *(const float4*)(wr + i * O_SZ);
            a00 = fmaf(xi0[i], wv.x, a00);
            a01 = fmaf(xi0[i], wv.y, a01);
            a02 = fmaf(xi0[i], wv.z, a02);
            a03 = fmaf(xi0[i], wv.w, a03);
            a10 = fmaf(xi1[i], wv.x, a10);
            a11 = fmaf(xi1[i], wv.y, a11);
            a12 = fmaf(xi1[i], wv.z, a12);
            a13 = fmaf(xi1[i], wv.w, a13);
        }
        P[0][j][0] = a00; P[0][j][1] = a01; P[0][j][2] = a02; P[0][j][3] = a03;
        P[1][j][0] = a10; P[1][j][1] = a11; P[1][j][2] = a12; P[1][j][3] = a13;
    }

    float logit[G_B][RPT];
    #pragma unroll
    for (int gb = 0; gb < G_B; ++gb)
        #pragma unroll
        for (int j = 0; j < RPT; ++j) logit[gb][j] = 0.0f;

    float outq[G_B][4];

    for (int it = 0; it < 3; ++it) {
        // ---- probs over r ----
        float p[G_B][RPT];
        if (it == 0) {
            const float u = 1.0f / (float)R_SZ;
            #pragma unroll
            for (int gb = 0; gb < G_B; ++gb)
                #pragma unroll
                for (int j = 0; j < RPT; ++j) p[gb][j] = u;
        } else {
            #pragma unroll
            for (int gb = 0; gb < G_B; ++gb) {
                float lm = logit[gb][0];
                #pragma unroll
                for (int j = 1; j < RPT; ++j) lm = fmaxf(lm, logit[gb][j]);
                #pragma unroll
                for (int m = 4; m <= 32; m <<= 1) lm = fmaxf(lm, __shfl_xor(lm, m, 64));
                if (lane == 0) red_max[wid][gb] = lm;
            }
            __syncthreads();
            #pragma unroll
            for (int gb = 0; gb < G_B; ++gb) {
                float gm = red_max[0][gb];
                #pragma unroll
                for (int k = 1; k < NW; ++k) gm = fmaxf(gm, red_max[k][gb]);
                float zp = 0.0f;
                #pragma unroll
                for (int j = 0; j < RPT; ++j) {
                    p[gb][j] = expf(logit[gb][j] - gm);
                    zp += p[gb][j];
                }
                #pragma unroll
                for (int m = 4; m <= 32; m <<= 1) zp += __shfl_xor(zp, m, 64);
                if (lane == 0) red_sum[wid][gb] = zp;
            }
            __syncthreads();
            #pragma unroll
            for (int gb = 0; gb < G_B; ++gb) {
                float Z = red_sum[0][gb];
                #pragma unroll
                for (int k = 1; k < NW; ++k) Z += red_sum[k][gb];
                const float invZ = 1.0f / Z;
                #pragma unroll
                for (int j = 0; j < RPT; ++j) p[gb][j] *= invZ;
            }
        }

        // ---- s and squash per batch ----
        #pragma unroll
        for (int gb = 0; gb < G_B; ++gb) {
            float sa[4] = {0.f, 0.f, 0.f, 0.f};
            #pragma unroll
            for (int j = 0; j < RPT; ++j) {
                sa[0] = fmaf(p[gb][j], P[gb][j][0], sa[0]);
                sa[1] = fmaf(p[gb][j], P[gb][j][1], sa[1]);
                sa[2] = fmaf(p[gb][j], P[gb][j][2], sa[2]);
                sa[3] = fmaf(p[gb][j], P[gb][j][3], sa[3]);
            }
            #pragma unroll
            for (int m = 4; m <= 32; m <<= 1) {
                sa[0] += __shfl_xor(sa[0], m, 64);
                sa[1] += __shfl_xor(sa[1], m, 64);
                sa[2] += __shfl_xor(sa[2], m, 64);
                sa[3] += __shfl_xor(sa[3], m, 64);
            }
            if (lane < 4) {
                red_s[wid][gb][lane][0] = sa[0];
                red_s[wid][gb][lane][1] = sa[1];
                red_s[wid][gb][lane][2] = sa[2];
                red_s[wid][gb][lane][3] = sa[3];
            }
        }
        __syncthreads();

        #pragma unroll
        for (int gb = 0; gb < G_B; ++gb) {
            float sv[4];
            #pragma unroll
            for (int k = 0; k < 4; ++k) {
                float v = red_s[0][gb][q][k];
                #pragma unroll
                for (int ww = 1; ww < NW; ++ww) v += red_s[ww][gb][q][k];
                sv[k] = v;
            }
            float nrm = sv[0]*sv[0] + sv[1]*sv[1] + sv[2]*sv[2] + sv[3]*sv[3];
            nrm += __shfl_xor(nrm, 1, 64);
            nrm += __shfl_xor(nrm, 2, 64);
            const float scale = nrm / ((1.0f + nrm) * sqrtf(nrm));
            #pragma unroll
            for (int k = 0; k < 4; ++k) outq[gb][k] = scale * sv[k];
        }

        // ---- logit update (iters 0,1) ----
        if (it < 2) {
            #pragma unroll
            for (int gb = 0; gb < G_B; ++gb) {
                #pragma unroll
                for (int j = 0; j < RPT; ++j) {
                    float d = P[gb][j][0]*outq[gb][0] + P[gb][j][1]*outq[gb][1]
                            + P[gb][j][2]*outq[gb][2] + P[gb][j][3]*outq[gb][3];
                    d += __shfl_xor(d, 1, 64);
                    d += __shfl_xor(d, 2, 64);
                    logit[gb][j] += d;
                }
            }
        }
        __syncthreads();
    }

    // ---- write out[b0+gb, c, :]: threads 0..3 hold quads 0..3 ----
    if (t < 4) {
        #pragma unroll
        for (int gb = 0; gb < G_B; ++gb) {
            float* op = out + ((size_t)(b0 + gb) * C_CAPS + c) * O_SZ + q * 4;
            *(float4*)op = make_float4(outq[gb][0], outq[gb][1], outq[gb][2], outq[gb][3]);
        }
    }
}

extern "C" void kernel_launch(void* const* d_in, const int* in_sizes, int n_in,
                              void* d_out, int out_size, void* d_ws, size_t ws_size,
                              hipStream_t stream) {
    const float* x = (const float*)d_in[0];
    const float* w = (const float*)d_in[1];
    float* out = (float*)d_out;
    dim3 grid(C_CAPS * (B_SZ / G_B));
    dim3 block(T_THREADS);
    hipLaunchKernelGGL(capsule_kernel, grid, block, 0, stream, x, w, out);
}

// Round 7
// 102.778 us; speedup vs baseline: 4.1552x; 1.0443x over previous
//
#include <hip/hip_runtime.h>
#include <math.h>

// Capsule dynamic routing — G=2 W-reuse with priors staged in LDS.
// Rounds 3-6 lesson: register-resident priors (~200 VGPR) always spilled to
// HBM scratch under the allocator's occupancy heuristics. This design spills
// deliberately to LDS instead (69 TB/s, software-managed): each thread writes
// and re-reads ONLY its own P elements, so LDS is a private register
// extension (no barriers needed for P). Per-thread VGPR state is now tiny.
//
// x: [B=256, R=1152, I=8] f32
// W: [C=10, R=1152, I=8, O=16] f32
// out: [B=256, C=10, O=16] f32
//
// One block per (c, b-pair). 768 threads = 192 groups of 4 lanes; 12 waves.
// Group g owns rows r = g + j*192 (j=0..5); lane q=t&3 owns o-quad.
// LDS P[2][1152][16] f32 dense: a wave's accesses cover a contiguous 1KB
// span (16 consecutive rows x 16 floats) -> conflict-free ds_*_b128.

#define C_CAPS 10
#define B_SZ   256
#define R_SZ   1152
#define I_SZ   8
#define O_SZ   16
#define G_B    2         // batches per block
#define T_THREADS 768
#define NGROUP 192       // T/4 groups
#define RPT 6            // rows per group = R / NGROUP
#define NW 12            // waves per block

__global__ __launch_bounds__(T_THREADS, 1) void capsule_kernel(
    const float* __restrict__ x,
    const float* __restrict__ w,
    float* __restrict__ out)
{
    const int c  = blockIdx.x >> 7;        // / (B/G)
    const int bb = blockIdx.x & 127;       // % (B/G)
    const int b0 = bb * G_B;
    const int t = (int)threadIdx.x;
    const int lane = t & 63;
    const int wid = t >> 6;
    const int q = t & 3;                   // o-quad index
    const int g = t >> 2;                  // group id 0..191

    __shared__ float Plds[G_B][R_SZ][O_SZ];          // 147456 B
    __shared__ float red_max[NW][G_B];
    __shared__ float red_sum[NW][G_B];
    __shared__ float red_s[NW][G_B][4][4];

    // ---- priors -> LDS: Plds[gb][r][q*4+k] for rows r = g + j*192 ----
    #pragma unroll
    for (int j = 0; j < RPT; ++j) {
        const int r = g + j * NGROUP;
        const float* xp = x + ((size_t)b0 * R_SZ + r) * I_SZ;
        const float4 x0a = *(const float4*)(xp);
        const float4 x0b = *(const float4*)(xp + 4);
        const float4 x1a = *(const float4*)(xp + (size_t)R_SZ * I_SZ);
        const float4 x1b = *(const float4*)(xp + (size_t)R_SZ * I_SZ + 4);
        const float xi0[I_SZ] = {x0a.x, x0a.y, x0a.z, x0a.w, x0b.x, x0b.y, x0b.z, x0b.w};
        const float xi1[I_SZ] = {x1a.x, x1a.y, x1a.z, x1a.w, x1b.x, x1b.y, x1b.z, x1b.w};

        const float* wr = w + ((size_t)c * R_SZ + r) * (I_SZ * O_SZ) + q * 4;
        float a00 = 0.f, a01 = 0.f, a02 = 0.f, a03 = 0.f;
        float a10 = 0.f, a11 = 0.f, a12 = 0.f, a13 = 0.f;
        #pragma unroll
        for (int i = 0; i < I_SZ; ++i) {
            const float4 wv = *(const float4*)(wr + i * O_SZ);
            a00 = fmaf(xi0[i], wv.x, a00);
            a01 = fmaf(xi0[i], wv.y, a01);
            a02 = fmaf(xi0[i], wv.z, a02);
            a03 = fmaf(xi0[i], wv.w, a03);
            a10 = fmaf(xi1[i], wv.x, a10);
            a11 = fmaf(xi1[i], wv.y, a11);
            a12 = fmaf(xi1[i], wv.z, a12);
            a13 = fmaf(xi1[i], wv.w, a13);
        }
        *(float4*)&Plds[0][r][q * 4] = make_float4(a00, a01, a02, a03);
        *(float4*)&Plds[1][r][q * 4] = make_float4(a10, a11, a12, a13);
    }

    float logit[G_B][RPT];
    #pragma unroll
    for (int gb = 0; gb < G_B; ++gb)
        #pragma unroll
        for (int j = 0; j < RPT; ++j) logit[gb][j] = 0.0f;

    float outq[G_B][4];

    for (int it = 0; it < 3; ++it) {
        // ---- probs over r ----
        float p[G_B][RPT];
        if (it == 0) {
            const float u = 1.0f / (float)R_SZ;
            #pragma unroll
            for (int gb = 0; gb < G_B; ++gb)
                #pragma unroll
                for (int j = 0; j < RPT; ++j) p[gb][j] = u;
        } else {
            #pragma unroll
            for (int gb = 0; gb < G_B; ++gb) {
                float lm = logit[gb][0];
                #pragma unroll
                for (int j = 1; j < RPT; ++j) lm = fmaxf(lm, logit[gb][j]);
                #pragma unroll
                for (int m = 4; m <= 32; m <<= 1) lm = fmaxf(lm, __shfl_xor(lm, m, 64));
                if (lane == 0) red_max[wid][gb] = lm;
            }
            __syncthreads();
            #pragma unroll
            for (int gb = 0; gb < G_B; ++gb) {
                float gm = red_max[0][gb];
                #pragma unroll
                for (int k = 1; k < NW; ++k) gm = fmaxf(gm, red_max[k][gb]);
                float zp = 0.0f;
                #pragma unroll
                for (int j = 0; j < RPT; ++j) {
                    p[gb][j] = expf(logit[gb][j] - gm);
                    zp += p[gb][j];
                }
                #pragma unroll
                for (int m = 4; m <= 32; m <<= 1) zp += __shfl_xor(zp, m, 64);
                if (lane == 0) red_sum[wid][gb] = zp;
            }
            __syncthreads();
            #pragma unroll
            for (int gb = 0; gb < G_B; ++gb) {
                float Z = red_sum[0][gb];
                #pragma unroll
                for (int k = 1; k < NW; ++k) Z += red_sum[k][gb];
                const float invZ = 1.0f / Z;
                #pragma unroll
                for (int j = 0; j < RPT; ++j) p[gb][j] *= invZ;
            }
        }

        // ---- s and squash per batch (P read from LDS: own elements only) ----
        #pragma unroll
        for (int gb = 0; gb < G_B; ++gb) {
            float sa[4] = {0.f, 0.f, 0.f, 0.f};
            #pragma unroll
            for (int j = 0; j < RPT; ++j) {
                const int r = g + j * NGROUP;
                const float4 Pv = *(const float4*)&Plds[gb][r][q * 4];
                sa[0] = fmaf(p[gb][j], Pv.x, sa[0]);
                sa[1] = fmaf(p[gb][j], Pv.y, sa[1]);
                sa[2] = fmaf(p[gb][j], Pv.z, sa[2]);
                sa[3] = fmaf(p[gb][j], Pv.w, sa[3]);
            }
            #pragma unroll
            for (int m = 4; m <= 32; m <<= 1) {
                sa[0] += __shfl_xor(sa[0], m, 64);
                sa[1] += __shfl_xor(sa[1], m, 64);
                sa[2] += __shfl_xor(sa[2], m, 64);
                sa[3] += __shfl_xor(sa[3], m, 64);
            }
            if (lane < 4) {
                red_s[wid][gb][lane][0] = sa[0];
                red_s[wid][gb][lane][1] = sa[1];
                red_s[wid][gb][lane][2] = sa[2];
                red_s[wid][gb][lane][3] = sa[3];
            }
        }
        __syncthreads();

        #pragma unroll
        for (int gb = 0; gb < G_B; ++gb) {
            float sv[4];
            #pragma unroll
            for (int k = 0; k < 4; ++k) {
                float v = red_s[0][gb][q][k];
                #pragma unroll
                for (int ww = 1; ww < NW; ++ww) v += red_s[ww][gb][q][k];
                sv[k] = v;
            }
            float nrm = sv[0]*sv[0] + sv[1]*sv[1] + sv[2]*sv[2] + sv[3]*sv[3];
            nrm += __shfl_xor(nrm, 1, 64);
            nrm += __shfl_xor(nrm, 2, 64);
            const float scale = nrm / ((1.0f + nrm) * sqrtf(nrm));
            #pragma unroll
            for (int k = 0; k < 4; ++k) outq[gb][k] = scale * sv[k];
        }

        // ---- logit update (iters 0,1) ----
        if (it < 2) {
            #pragma unroll
            for (int gb = 0; gb < G_B; ++gb) {
                #pragma unroll
                for (int j = 0; j < RPT; ++j) {
                    const int r = g + j * NGROUP;
                    const float4 Pv = *(const float4*)&Plds[gb][r][q * 4];
                    float d = Pv.x*outq[gb][0] + Pv.y*outq[gb][1]
                            + Pv.z*outq[gb][2] + Pv.w*outq[gb][3];
                    d += __shfl_xor(d, 1, 64);
                    d += __shfl_xor(d, 2, 64);
                    logit[gb][j] += d;
                }
            }
        }
        __syncthreads();
    }

    // ---- write out[b0+gb, c, :]: threads 0..3 hold quads 0..3 ----
    if (t < 4) {
        #pragma unroll
        for (int gb = 0; gb < G_B; ++gb) {
            float* op = out + ((size_t)(b0 + gb) * C_CAPS + c) * O_SZ + q * 4;
            *(float4*)op = make_float4(outq[gb][0], outq[gb][1], outq[gb][2], outq[gb][3]);
        }
    }
}

extern "C" void kernel_launch(void* const* d_in, const int* in_sizes, int n_in,
                              void* d_out, int out_size, void* d_ws, size_t ws_size,
                              hipStream_t stream) {
    const float* x = (const float*)d_in[0];
    const float* w = (const float*)d_in[1];
    float* out = (float*)d_out;
    dim3 grid(C_CAPS * (B_SZ / G_B));
    dim3 block(T_THREADS);
    hipLaunchKernelGGL(capsule_kernel, grid, block, 0, stream, x, w, out);
}

// Round 8
// 88.212 us; speedup vs baseline: 4.8413x; 1.1651x over previous
//
#include <hip/hip_runtime.h>
#include <math.h>

// Capsule dynamic routing v9 — DS-pipe-minimized design.
// Lessons: R2 vs R7 showed W-L2 bandwidth is NOT binding; the routing
// iterations' DS-pipe work (LDS P reads + broadcast combines + shuffles) and
// reduction latency chains are. v9: P in registers (G=1, 48 floats, fits the
// measured (384,1)->128 VGPR cap), softmax max-pass dropped (|logit|<=~40 so
// f32 exp is safe), Z folded into the s-reduction -> ONE 5-float block
// reduction per iteration (was 3 rounds), one-wave combine + broadcast.
//
// x: [B=256, R=1152, I=8] f32
// W: [C=10, R=1152, I=8, O=16] f32
// out: [B=256, C=10, O=16] f32
//
// One block per (c,b). 384 threads = 96 groups of 4 lanes.
// Group g owns rows r = g + j*96 (j=0..11); lane q=t&3 owns o-quad.

#define C_CAPS 10
#define B_SZ   256
#define R_SZ   1152
#define I_SZ   8
#define O_SZ   16
#define T_THREADS 384
#define NGROUP 96        // T/4 groups
#define RPT 12           // rows per group
#define NW 6             // waves per block

__global__ __launch_bounds__(T_THREADS, 1) void capsule_kernel(
    const float* __restrict__ x,
    const float* __restrict__ w,
    float* __restrict__ out)
{
    const int c = blockIdx.x >> 8;        // / B_SZ
    const int b = blockIdx.x & 255;       // % B_SZ
    const int t = (int)threadIdx.x;
    const int lane = t & 63;
    const int wid = t >> 6;
    const int q = t & 3;                  // o-quad index
    const int g = t >> 2;                 // group id 0..95

    __shared__ float4 red_s[NW][4];       // per-wave s-partial, [wave][q]
    __shared__ float  red_z[NW];          // per-wave Z-partial
    __shared__ float4 s_fin[4];           // combined s_red per q
    __shared__ float  z_fin;              // combined Z

    // ---- priors: P[j][k] = priors[r = g + j*96][o = q*4+k]  (registers) ----
    float P[RPT][4];
    #pragma unroll
    for (int j = 0; j < RPT; ++j) {
        const int r = g + j * NGROUP;
        const float* xp = x + ((size_t)b * R_SZ + r) * I_SZ;
        const float4 xv0 = *(const float4*)(xp);       // broadcast within group
        const float4 xv1 = *(const float4*)(xp + 4);
        const float xi[I_SZ] = {xv0.x, xv0.y, xv0.z, xv0.w,
                                xv1.x, xv1.y, xv1.z, xv1.w};
        const float* wr = w + ((size_t)c * R_SZ + r) * (I_SZ * O_SZ) + q * 4;
        float a0 = 0.f, a1 = 0.f, a2 = 0.f, a3 = 0.f;
        #pragma unroll
        for (int i = 0; i < I_SZ; ++i) {
            const float4 wv = *(const float4*)(wr + i * O_SZ);
            a0 = fmaf(xi[i], wv.x, a0);
            a1 = fmaf(xi[i], wv.y, a1);
            a2 = fmaf(xi[i], wv.z, a2);
            a3 = fmaf(xi[i], wv.w, a3);
        }
        P[j][0] = a0; P[j][1] = a1; P[j][2] = a2; P[j][3] = a3;
    }

    float logit[RPT];
    #pragma unroll
    for (int j = 0; j < RPT; ++j) logit[j] = 0.0f;

    float vq[4];   // this lane's o-quad of the squashed output

    for (int it = 0; it < 3; ++it) {
        // ---- fused exp + weighted-sum partials (no max pass; |logit|<=~40,
        //      exp<=e^40 and Z<=1152*e^40 are safely inside f32 range) ----
        float sa0 = 0.f, sa1 = 0.f, sa2 = 0.f, sa3 = 0.f, zp = 0.f;
        #pragma unroll
        for (int j = 0; j < RPT; ++j) {
            const float e = __expf(logit[j]);   // it==0: exp(0)=1 exactly
            zp += e;
            sa0 = fmaf(e, P[j][0], sa0);
            sa1 = fmaf(e, P[j][1], sa1);
            sa2 = fmaf(e, P[j][2], sa2);
            sa3 = fmaf(e, P[j][3], sa3);
        }
        // single reduction round: {sa0..3, zp} across the wave's 16 groups
        #pragma unroll
        for (int m = 4; m <= 32; m <<= 1) {
            sa0 += __shfl_xor(sa0, m, 64);
            sa1 += __shfl_xor(sa1, m, 64);
            sa2 += __shfl_xor(sa2, m, 64);
            sa3 += __shfl_xor(sa3, m, 64);
            zp  += __shfl_xor(zp,  m, 64);
        }
        if (lane < 4) red_s[wid][lane] = make_float4(sa0, sa1, sa2, sa3);
        if (lane == 0) red_z[wid] = zp;
        __syncthreads();

        // ---- one-wave combine (threads 0..4), then broadcast ----
        if (t < 4) {
            float4 a = red_s[0][t];
            #pragma unroll
            for (int ww = 1; ww < NW; ++ww) {
                const float4 rr = red_s[ww][t];
                a.x += rr.x; a.y += rr.y; a.z += rr.z; a.w += rr.w;
            }
            s_fin[t] = a;
        }
        if (t == 4) {
            float zz = red_z[0];
            #pragma unroll
            for (int ww = 1; ww < NW; ++ww) zz += red_z[ww];
            z_fin = zz;
        }
        __syncthreads();

        // ---- normalize + squash (normalize BEFORE squaring: overflow-safe) ----
        const float invZ = 1.0f / z_fin;
        const float4 sf = s_fin[q];
        const float u0 = sf.x * invZ, u1 = sf.y * invZ,
                    u2 = sf.z * invZ, u3 = sf.w * invZ;
        float nq = u0*u0 + u1*u1 + u2*u2 + u3*u3;
        nq += __shfl_xor(nq, 1, 64);
        nq += __shfl_xor(nq, 2, 64);
        const float scale = nq / ((1.0f + nq) * sqrtf(nq));
        vq[0] = scale * u0; vq[1] = scale * u1;
        vq[2] = scale * u2; vq[3] = scale * u3;

        // ---- logit update (iters 0,1): logit[r] += P[r]·v ----
        if (it < 2) {
            #pragma unroll
            for (int j = 0; j < RPT; ++j) {
                float d = P[j][0]*vq[0] + P[j][1]*vq[1]
                        + P[j][2]*vq[2] + P[j][3]*vq[3];
                d += __shfl_xor(d, 1, 64);
                d += __shfl_xor(d, 2, 64);
                logit[j] += d;
            }
        }
        // no end-of-iter barrier needed: red_s/red_z rewrites happen only
        // after the next iteration's barrier #1; s_fin reads complete before
        // any thread reaches that barrier.
    }

    // ---- write out[b, c, :]: threads 0..3 hold quads 0..3 ----
    if (t < 4) {
        float* op = out + ((size_t)b * C_CAPS + c) * O_SZ + q * 4;
        *(float4*)op = make_float4(vq[0], vq[1], vq[2], vq[3]);
    }
}

extern "C" void kernel_launch(void* const* d_in, const int* in_sizes, int n_in,
                              void* d_out, int out_size, void* d_ws, size_t ws_size,
                              hipStream_t stream) {
    const float* x = (const float*)d_in[0];
    const float* w = (const float*)d_in[1];
    float* out = (float*)d_out;
    dim3 grid(C_CAPS * B_SZ);
    dim3 block(T_THREADS);
    hipLaunchKernelGGL(capsule_kernel, grid, block, 0, stream, x, w, out);
}

// Round 9
// 72.507 us; speedup vs baseline: 5.8900x; 1.2166x over previous
//
#include <hip/hip_runtime.h>
#include <math.h>

// Capsule dynamic routing v10 — MLP-pipelined prior phase + wider blocks.
// R8 diagnosis: VGPR=52 -> only ~3-4 W-loads in flight -> latency-bound on
// the W stream (17 TB/s effective, no ceiling hit). v10: (1) explicit 1-row
// W/x lookahead forces ~2x outstanding loads; (2) T=512 (RPT=9) adds waves
// for latency hiding and shrinks per-thread serial routing work.
// Routing keeps v9's fused form: no max pass (|logit|<=~40 safe in f32),
// Z folded into the s-reduction, single 5-float block reduction per iter.
//
// x: [B=256, R=1152, I=8] f32
// W: [C=10, R=1152, I=8, O=16] f32
// out: [B=256, C=10, O=16] f32
//
// One block per (c,b). 512 threads = 128 groups of 4 lanes; 8 waves.
// Group g owns rows r = g + j*128 (j=0..8); lane q=t&3 owns o-quad.

#define C_CAPS 10
#define B_SZ   256
#define R_SZ   1152
#define I_SZ   8
#define O_SZ   16
#define T_THREADS 512
#define NGROUP 128       // T/4 groups
#define RPT 9            // rows per group = R / NGROUP
#define NW 8             // waves per block

__global__ __launch_bounds__(T_THREADS, 1) void capsule_kernel(
    const float* __restrict__ x,
    const float* __restrict__ w,
    float* __restrict__ out)
{
    const int c = blockIdx.x >> 8;        // / B_SZ
    const int b = blockIdx.x & 255;       // % B_SZ
    const int t = (int)threadIdx.x;
    const int lane = t & 63;
    const int wid = t >> 6;
    const int q = t & 3;                  // o-quad index
    const int g = t >> 2;                 // group id 0..127

    __shared__ float4 red_s[NW][4];       // per-wave s-partial, [wave][q]
    __shared__ float  red_z[NW];          // per-wave Z-partial
    __shared__ float4 s_fin[4];           // combined s per q
    __shared__ float  z_fin;              // combined Z

    // ---- priors with 1-row lookahead: P[j][k], rows r = g + j*128 ----
    float P[RPT][4];

    const float* xbase = x + ((size_t)b * R_SZ + g) * I_SZ;
    const float* wbase = w + ((size_t)c * R_SZ + g) * (I_SZ * O_SZ) + q * 4;
    const size_t xstep = (size_t)NGROUP * I_SZ;            // row stride over j
    const size_t wstep = (size_t)NGROUP * I_SZ * O_SZ;

    // preload row j=0
    float4 xc0 = *(const float4*)(xbase);
    float4 xc1 = *(const float4*)(xbase + 4);
    float4 wc[8];
    #pragma unroll
    for (int i = 0; i < I_SZ; ++i) wc[i] = *(const float4*)(wbase + i * O_SZ);

    #pragma unroll
    for (int j = 0; j < RPT; ++j) {
        // prefetch row j+1 while computing row j
        float4 xn0, xn1, wn[8];
        if (j < RPT - 1) {
            const float* xp = xbase + (j + 1) * xstep;
            const float* wp = wbase + (j + 1) * wstep;
            xn0 = *(const float4*)(xp);
            xn1 = *(const float4*)(xp + 4);
            #pragma unroll
            for (int i = 0; i < I_SZ; ++i) wn[i] = *(const float4*)(wp + i * O_SZ);
        }
        const float xi[I_SZ] = {xc0.x, xc0.y, xc0.z, xc0.w,
                                xc1.x, xc1.y, xc1.z, xc1.w};
        float a0 = 0.f, a1 = 0.f, a2 = 0.f, a3 = 0.f;
        #pragma unroll
        for (int i = 0; i < I_SZ; ++i) {
            a0 = fmaf(xi[i], wc[i].x, a0);
            a1 = fmaf(xi[i], wc[i].y, a1);
            a2 = fmaf(xi[i], wc[i].z, a2);
            a3 = fmaf(xi[i], wc[i].w, a3);
        }
        P[j][0] = a0; P[j][1] = a1; P[j][2] = a2; P[j][3] = a3;
        if (j < RPT - 1) {
            xc0 = xn0; xc1 = xn1;
            #pragma unroll
            for (int i = 0; i < I_SZ; ++i) wc[i] = wn[i];
        }
    }

    float logit[RPT];
    #pragma unroll
    for (int j = 0; j < RPT; ++j) logit[j] = 0.0f;

    float vq[4];   // this lane's o-quad of the squashed output

    for (int it = 0; it < 3; ++it) {
        // ---- fused exp + weighted-sum partials (no max pass) ----
        float sa0 = 0.f, sa1 = 0.f, sa2 = 0.f, sa3 = 0.f, zp = 0.f;
        #pragma unroll
        for (int j = 0; j < RPT; ++j) {
            const float e = __expf(logit[j]);   // it==0: exp(0)=1 exactly
            zp += e;
            sa0 = fmaf(e, P[j][0], sa0);
            sa1 = fmaf(e, P[j][1], sa1);
            sa2 = fmaf(e, P[j][2], sa2);
            sa3 = fmaf(e, P[j][3], sa3);
        }
        // one reduction round: {sa0..3, zp} across the wave's 16 groups
        #pragma unroll
        for (int m = 4; m <= 32; m <<= 1) {
            sa0 += __shfl_xor(sa0, m, 64);
            sa1 += __shfl_xor(sa1, m, 64);
            sa2 += __shfl_xor(sa2, m, 64);
            sa3 += __shfl_xor(sa3, m, 64);
            zp  += __shfl_xor(zp,  m, 64);
        }
        if (lane < 4) red_s[wid][lane] = make_float4(sa0, sa1, sa2, sa3);
        if (lane == 0) red_z[wid] = zp;
        __syncthreads();

        // ---- one-wave combine (threads 0..4), then broadcast ----
        if (t < 4) {
            float4 a = red_s[0][t];
            #pragma unroll
            for (int ww = 1; ww < NW; ++ww) {
                const float4 rr = red_s[ww][t];
                a.x += rr.x; a.y += rr.y; a.z += rr.z; a.w += rr.w;
            }
            s_fin[t] = a;
        }
        if (t == 4) {
            float zz = red_z[0];
            #pragma unroll
            for (int ww = 1; ww < NW; ++ww) zz += red_z[ww];
            z_fin = zz;
        }
        __syncthreads();

        // ---- normalize + squash (normalize BEFORE squaring: overflow-safe) ----
        const float invZ = 1.0f / z_fin;
        const float4 sf = s_fin[q];
        const float u0 = sf.x * invZ, u1 = sf.y * invZ,
                    u2 = sf.z * invZ, u3 = sf.w * invZ;
        float nq = u0*u0 + u1*u1 + u2*u2 + u3*u3;
        nq += __shfl_xor(nq, 1, 64);
        nq += __shfl_xor(nq, 2, 64);
        const float scale = nq / ((1.0f + nq) * sqrtf(nq));
        vq[0] = scale * u0; vq[1] = scale * u1;
        vq[2] = scale * u2; vq[3] = scale * u3;

        // ---- logit update (iters 0,1): logit[r] += P[r]·v ----
        if (it < 2) {
            #pragma unroll
            for (int j = 0; j < RPT; ++j) {
                float d = P[j][0]*vq[0] + P[j][1]*vq[1]
                        + P[j][2]*vq[2] + P[j][3]*vq[3];
                d += __shfl_xor(d, 1, 64);
                d += __shfl_xor(d, 2, 64);
                logit[j] += d;
            }
        }
        // no end-of-iter barrier needed: red_s/red_z rewrites occur only after
        // the next iteration's barrier #1; s_fin reads complete before it.
    }

    // ---- write out[b, c, :]: threads 0..3 hold quads 0..3 ----
    if (t < 4) {
        float* op = out + ((size_t)b * C_CAPS + c) * O_SZ + q * 4;
        *(float4*)op = make_float4(vq[0], vq[1], vq[2], vq[3]);
    }
}

extern "C" void kernel_launch(void* const* d_in, const int* in_sizes, int n_in,
                              void* d_out, int out_size, void* d_ws, size_t ws_size,
                              hipStream_t stream) {
    const float* x = (const float*)d_in[0];
    const float* w = (const float*)d_in[1];
    float* out = (float*)d_out;
    dim3 grid(C_CAPS * B_SZ);
    dim3 block(T_THREADS);
    hipLaunchKernelGGL(capsule_kernel, grid, block, 0, stream, x, w, out);
}